// Round 9
// baseline (128.667 us; speedup 1.0000x reference)
//
#include <hip/hip_runtime.h>
#include <hip/hip_bf16.h>

// Problem constants (from reference): N=100000, F=128, E=640000, OUT=16
#define F_DIM 128
#define OUT_DIM 16

typedef _Float16 half8 __attribute__((ext_vector_type(8)));
typedef float floatx4 __attribute__((ext_vector_type(4)));
typedef unsigned short us8 __attribute__((ext_vector_type(8)));

__device__ __forceinline__ unsigned bf16_bits_rne(float f) {
    unsigned u = __builtin_bit_cast(unsigned, f);
    unsigned rounding = 0x7FFFu + ((u >> 16) & 1u);
    return (u + rounding) >> 16;          // RNE; NaN not possible here
}

// ---------------------------------------------------------------------------
// Kernel 1: Pu16[node][o] = bf16(h[node].Wu + b) ; Pv16 likewise (no bias).
// TRANSPOSED MFMA (proven R8): D[m=o][n=node] = sum_k W'[o][k]*h[node][k]
//   A = weight frag (lane&15 -> o, quad*8+j -> k)  — now loaded DIRECTLY from
//       global W in-register (wprep kernel fused away; W is 128KB, L2-hot)
//   B = h frag (lane&15 -> node, quad*8+j -> k)
//   D: row = quad*4+reg = o, col = lane&15 = node
// Single fp16 MFMA per half per k-step (hi/lo split dropped: residual dot
// error ~2e-4 RMS, ~100x below the bf16 table quantum that dominates).
// Epilogue: in-register RNE bf16 pack, dword-only stores (proven R8).
__global__ __launch_bounds__(256) void proj_mfma_kernel(
    const float* __restrict__ h, const float* __restrict__ W,
    const float* __restrict__ b,
    unsigned int* __restrict__ Pu16, unsigned int* __restrict__ Pv16, int N)
{
    const int lane = threadIdx.x & 63;
    const int wave = threadIdx.x >> 6;
    const int n = lane & 15;            // A: output index o ; B/D: node column
    const int q = lane >> 4;            // quad: k-group / o-group selector
    const int row_base = blockIdx.x * 64 + wave * 16;
    if (row_base >= N) return;          // whole wave exits; no barriers below

    // ---- W fragments, loaded once into registers (16 x dwordx4, L2-hot) ----
    // wf[t*4+s][j] = W[n*256 + t*128 + s*32 + q*8 + j]
    const float* wbase = W + n * 256 + q * 8;
    half8 wf[8];
    #pragma unroll
    for (int t = 0; t < 2; ++t) {
        #pragma unroll
        for (int s = 0; s < 4; ++s) {
            float wv[8];
            *(float4*)(wv)     = *(const float4*)(wbase + t * 128 + s * 32);
            *(float4*)(wv + 4) = *(const float4*)(wbase + t * 128 + s * 32 + 4);
            half8 f;
            #pragma unroll
            for (int j = 0; j < 8; ++j) f[j] = (_Float16)wv[j];
            wf[t * 4 + s] = f;
        }
    }

    int arow = row_base + n;            // h row this lane feeds (B operand)
    if (arow >= N) arow = N - 1;        // clamped rows -> unstored D columns
    const float* hrow = h + (size_t)arow * F_DIM + q * 8;

    floatx4 c0 = {0.f, 0.f, 0.f, 0.f};   // u half: D[o][node]
    floatx4 c1 = {0.f, 0.f, 0.f, 0.f};   // v half

    #pragma unroll
    for (int s = 0; s < 4; ++s) {
        float av[8];
        *(float4*)(av)     = *(const float4*)(hrow + s * 32);
        *(float4*)(av + 4) = *(const float4*)(hrow + s * 32 + 4);
        half8 ah;
        #pragma unroll
        for (int j = 0; j < 8; ++j) ah[j] = (_Float16)av[j];

        c0 = __builtin_amdgcn_mfma_f32_16x16x32_f16(wf[s],     ah, c0, 0, 0, 0);
        c1 = __builtin_amdgcn_mfma_f32_16x16x32_f16(wf[4 + s], ah, c1, 0, 0, 0);
    }

    const int node = row_base + n;      // D column this lane owns
    if (node < N) {
        const floatx4 bv = *(const floatx4*)(b + 4 * q);   // b[4q+reg]
        unsigned u0 = bf16_bits_rne(c0[0] + bv[0]) | (bf16_bits_rne(c0[1] + bv[1]) << 16);
        unsigned u1 = bf16_bits_rne(c0[2] + bv[2]) | (bf16_bits_rne(c0[3] + bv[3]) << 16);
        unsigned v0 = bf16_bits_rne(c1[0]) | (bf16_bits_rne(c1[1]) << 16);
        unsigned v1 = bf16_bits_rne(c1[2]) | (bf16_bits_rne(c1[3]) << 16);
        const size_t base = (size_t)node * 8 + 2 * q;
        Pu16[base]     = u0;
        Pu16[base + 1] = u1;
        Pv16[base]     = v0;
        Pv16[base + 1] = v1;
    }
}

// ---------------------------------------------------------------------------
// Kernel 2: out[e][o] = Pu[src[e]][o] + Pv[dst[e]][o]   (bias already in Pu)
// Byte-identical to R7/R8's passing gather: 2 lanes/edge, 16B bf16 loads per
// table, <<16 converts, 32B contiguous NT stores.
__global__ __launch_bounds__(256) void gather_kernel(
    const unsigned short* __restrict__ Pu, const unsigned short* __restrict__ Pv,
    const int* __restrict__ src, const int* __restrict__ dst,
    float* __restrict__ out, int E)
{
    const int tid = blockIdx.x * blockDim.x + threadIdx.x;
    const int e = tid >> 1;
    const int q = tid & 1;
    if (e >= E) return;
    const int s = src[e];
    const int d = dst[e];
    const us8 pu = *(const us8*)(Pu + (size_t)s * 16 + q * 8);
    const us8 pv = *(const us8*)(Pv + (size_t)d * 16 + q * 8);
    floatx4 r0, r1;
    #pragma unroll
    for (int j = 0; j < 4; ++j) {
        r0[j] = __uint_as_float((unsigned)pu[j] << 16)
              + __uint_as_float((unsigned)pv[j] << 16);
        r1[j] = __uint_as_float((unsigned)pu[j + 4] << 16)
              + __uint_as_float((unsigned)pv[j + 4] << 16);
    }
    floatx4* o = (floatx4*)out + (size_t)tid * 2;
    __builtin_nontemporal_store(r0, o);
    __builtin_nontemporal_store(r1, o + 1);
}

// Fallback (only if workspace too small): direct per-(edge,out) dot, fp32.
__global__ __launch_bounds__(256) void direct_kernel(
    const float* __restrict__ h, const int* __restrict__ src,
    const int* __restrict__ dst, const float* __restrict__ W,
    const float* __restrict__ b, float* __restrict__ out, int E)
{
    const int tid = blockIdx.x * blockDim.x + threadIdx.x;
    if (tid >= E * OUT_DIM) return;
    const int e = tid >> 4;
    const int o = tid & 15;
    const float* hu = h + (size_t)src[e] * F_DIM;
    const float* hv = h + (size_t)dst[e] * F_DIM;
    const float* wu = W + (size_t)o * 256;
    const float* wv = wu + 128;
    float acc = b[o];
    for (int k = 0; k < 128; ++k) acc = fmaf(hu[k], wu[k], acc);
    for (int k = 0; k < 128; ++k) acc = fmaf(hv[k], wv[k], acc);
    out[tid] = acc;
}

extern "C" void kernel_launch(void* const* d_in, const int* in_sizes, int n_in,
                              void* d_out, int out_size, void* d_ws, size_t ws_size,
                              hipStream_t stream) {
    const float* h   = (const float*)d_in[0];
    const int*   src = (const int*)d_in[1];
    const int*   dst = (const int*)d_in[2];
    const float* W   = (const float*)d_in[3];
    const float* b   = (const float*)d_in[4];
    float* out = (float*)d_out;

    const int N = in_sizes[0] / F_DIM;     // 100000
    const int E = in_sizes[1];             // 640000

    const size_t p16_bytes = (size_t)N * 8 * sizeof(unsigned);    // 3.2 MB
    const size_t p16_al    = (p16_bytes + 255) & ~(size_t)255;

    if (ws_size >= 2 * p16_al) {
        unsigned int* Pu16 = (unsigned int*)d_ws;
        unsigned int* Pv16 = (unsigned int*)((char*)d_ws + p16_al);

        const int blocks1 = (N + 63) / 64;
        proj_mfma_kernel<<<blocks1, 256, 0, stream>>>(h, W, b, Pu16, Pv16, N);

        const int total2  = E * 2;
        const int blocks2 = (total2 + 255) / 256;
        gather_kernel<<<blocks2, 256, 0, stream>>>(
            (const unsigned short*)Pu16, (const unsigned short*)Pv16,
            src, dst, out, E);
    } else {
        const int total  = E * OUT_DIM;
        const int blocks = (total + 255) / 256;
        direct_kernel<<<blocks, 256, 0, stream>>>(h, src, dst, W, b, out, E);
    }
}